// Round 2
// baseline (177.295 us; speedup 1.0000x reference)
//
#include <hip/hip_runtime.h>
#include <hip/hip_cooperative_groups.h>

namespace cg = cooperative_groups;

// Problem constants: [T+1, B] = [1024, 4096] fp32, time-major
#define T1     1024
#define T      1023
#define B      4096
#define Q      1024   // B/4 column-quads per row
#define CHUNK  16
#define NCHUNK 64     // chunk c covers t in [16c, min(16c+16, 1023))
#define GPC    4      // column-groups per chunk (1024 cols = 256 quads each)
#define QB     256    // quads per block (== blockDim.x, 1 quad/thread)
#define RETAIN 12     // steps per chunk cached in LDS (3 planes * 12 * 256 * 16B = 144 KiB)

#define GAMMA     0.99f
#define TD_LAMBDA 0.95f

typedef __attribute__((ext_vector_type(4))) float f4;
typedef __attribute__((ext_vector_type(4))) int   i4;

// Single-pass fused kernel (cooperative, 256 blocks == 256 CUs, 1 block/CU):
//  Phase 1: per (chunk, col-quad) compose the chunk's affine steps
//           adv[s] = A + Bf * adv[e], stashing per-step replay state
//           (a = nl*delta, b = nl*wd, m = tv - value) for the low RETAIN
//           steps in LDS. Publishes (A, Bf) chunk aggregates to workspace.
//  grid.sync()
//  Phase 2: suffix-walk the chunk aggregates (2 MiB, L2-resident) to get the
//           right-boundary adv, then replay: top (CHUNK-RETAIN) steps by
//           recompute (L3-hot re-read), low RETAIN steps pure-LDS.
__global__ __launch_bounds__(256) void k_fused(
    const float* __restrict__ value, const float* __restrict__ tv,
    const float* __restrict__ rew, const int* __restrict__ st,
    const float* __restrict__ disc,
    float* __restrict__ AggA, float* __restrict__ AggB,
    float* __restrict__ out)
{
    __shared__ f4 a_lds[RETAIN][QB];
    __shared__ f4 b_lds[RETAIN][QB];
    __shared__ f4 m_lds[RETAIN][QB];

    int c = blockIdx.x >> 2;          // chunk 0..63
    int g = blockIdx.x & 3;           // column group 0..3
    int q = (g << 8) + threadIdx.x;   // global quad index 0..1023
    int s = c * CHUNK;
    int e = min(s + CHUNK, T);        // e-s is 16, except 15 for c=63

    const f4* tv4   = (const f4*)tv;
    const f4* rew4  = (const f4*)rew;
    const f4* disc4 = (const f4*)disc;
    const f4* val4  = (const f4*)value;
    const i4* st4   = (const i4*)st;
    f4* A4 = (f4*)AggA;
    f4* B4 = (f4*)AggB;
    f4* out4 = (f4*)out;

    // ---- Phase 1: compose + stash ----
    f4 A  = {0.f, 0.f, 0.f, 0.f};
    f4 Bf = {1.f, 1.f, 1.f, 1.f};
    f4 tvn = tv4[(size_t)e * Q + q];          // tv[t+1] for highest-t step
#pragma unroll 4
    for (int t = e - 1; t >= s; --t) {
        size_t i  = (size_t)t * Q + q;
        size_t i1 = i + Q;
        f4 d1  = disc4[i1] * GAMMA;
        f4 tvt = tv4[i];
        f4 r1  = rew4[i1];
        i4 stt = st4[i];
        f4 a, bb;
#pragma unroll
        for (int j = 0; j < 4; ++j) {
            float delta = r1[j] + d1[j] * tvn[j] - tvt[j];
            float wd    = d1[j] * TD_LAMBDA;
            float nl    = (stt[j] == 2) ? 0.f : 1.f;
            a[j]  = nl * delta;
            bb[j] = nl * wd;
            A[j]  = fmaf(bb[j], A[j], a[j]);
            Bf[j] *= bb[j];
        }
        int r = t - s;
        if (r < RETAIN) {
            f4 vv = val4[i];                  // only loaded for retained steps
            a_lds[r][threadIdx.x] = a;
            b_lds[r][threadIdx.x] = bb;
            m_lds[r][threadIdx.x] = tvt - vv;
        }
        tvn = tvt;
    }
    A4[c * Q + q] = A;
    B4[c * Q + q] = Bf;

    cg::this_grid().sync();

    // ---- Phase 2a: suffix walk over chunk aggregates (L2-resident, 2 MiB) ----
    f4 S = {0.f, 0.f, 0.f, 0.f};
    f4 P = {1.f, 1.f, 1.f, 1.f};
    for (int cc = c + 1; cc < NCHUNK; ++cc) {
        f4 aa = A4[cc * Q + q];
        f4 bb = B4[cc * Q + q];
#pragma unroll
        for (int j = 0; j < 4; ++j) {
            S[j] = fmaf(P[j], aa[j], S[j]);
            P[j] *= bb[j];
        }
    }
    f4 adv = S;   // adv at t = e(c); terminal adv[T] = 0

    if (c == NCHUNK - 1) {
        // tensor_extend_zero: last output row is zeros (d_out poisoned, must write)
        f4 z = {0.f, 0.f, 0.f, 0.f};
        out4[(size_t)T * Q + q] = z;
    }

    // ---- Phase 2b: recompute top steps t in [s+RETAIN, e) (L3-hot re-read) ----
    f4 tvn2 = tv4[(size_t)e * Q + q];
#pragma unroll
    for (int t = e - 1; t >= s + RETAIN; --t) {
        size_t i  = (size_t)t * Q + q;
        size_t i1 = i + Q;
        f4 d1  = disc4[i1] * GAMMA;
        f4 tvt = tv4[i];
        f4 r1  = rew4[i1];
        i4 stt = st4[i];
        f4 vv  = val4[i];
        f4 o;
#pragma unroll
        for (int j = 0; j < 4; ++j) {
            float delta = r1[j] + d1[j] * tvn2[j] - tvt[j];
            float wd    = d1[j] * TD_LAMBDA;
            float nl    = (stt[j] == 2) ? 0.f : 1.f;
            adv[j] = nl * fmaf(wd, adv[j], delta);
            float td = adv[j] + tvt[j] - vv[j];
            o[j] = td * td;
        }
        out4[i] = o;
        tvn2 = tvt;
    }

    // ---- Phase 2c: pure-LDS replay for t in [s, s+RETAIN) ----
#pragma unroll
    for (int r = RETAIN - 1; r >= 0; --r) {
        size_t i = (size_t)(s + r) * Q + q;
        f4 aa = a_lds[r][threadIdx.x];
        f4 bb = b_lds[r][threadIdx.x];
        f4 mm = m_lds[r][threadIdx.x];
        f4 o;
#pragma unroll
        for (int j = 0; j < 4; ++j) {
            adv[j] = fmaf(bb[j], adv[j], aa[j]);
            float td = adv[j] + mm[j];
            o[j] = td * td;
        }
        out4[i] = o;
    }
}

extern "C" void kernel_launch(void* const* d_in, const int* in_sizes, int n_in,
                              void* d_out, int out_size, void* d_ws, size_t ws_size,
                              hipStream_t stream) {
    // setup_inputs order: value, target_value, reward, step_type, discount
    const float* value = (const float*)d_in[0];
    const float* tv    = (const float*)d_in[1];
    const float* rew   = (const float*)d_in[2];
    const int*   st    = (const int*)d_in[3];
    const float* disc  = (const float*)d_in[4];
    float* out = (float*)d_out;

    // Workspace: 2 arrays of NCHUNK*B floats = 2 MiB total
    float* AggA = (float*)d_ws;
    float* AggB = AggA + (size_t)NCHUNK * B;

    void* args[] = {(void*)&value, (void*)&tv, (void*)&rew, (void*)&st,
                    (void*)&disc, (void*)&AggA, (void*)&AggB, (void*)&out};
    hipLaunchCooperativeKernel((void*)k_fused, dim3(NCHUNK * GPC), dim3(256),
                               args, 0, stream);
}

// Round 3
// 135.724 us; speedup vs baseline: 1.3063x; 1.3063x over previous
//
#include <hip/hip_runtime.h>

// Problem constants: [T+1, B] = [1024, 4096] fp32, time-major
#define T1     1024
#define T      1023
#define B      4096
#define Q      1024   // B/4 column-quads per row
#define CHUNK  16
#define NCHUNK 64     // chunk c covers t in [16c, min(16c+16, 1023))
#define GPC    4      // column-groups per chunk (1024 cols = 256 quads each) -> 256 blocks

#define GAMMA     0.99f
#define TD_LAMBDA 0.95f

typedef __attribute__((ext_vector_type(4))) float f4;
typedef __attribute__((ext_vector_type(4))) int   i4;

// Phase 1: per (chunk, col-quad), compose the chunk's affine steps
// adv[t] = a_t + b_t*adv[t+1]  into  adv[s] = A + Bf*adv[e].  float4 across columns.
__global__ __launch_bounds__(256) void k_compose(
    const float* __restrict__ tv, const float* __restrict__ rew,
    const int* __restrict__ st, const float* __restrict__ disc,
    float* __restrict__ AggA, float* __restrict__ AggB)
{
    int c = blockIdx.x >> 2;          // chunk 0..63
    int g = blockIdx.x & 3;           // column group 0..3
    int q = (g << 8) + threadIdx.x;   // quad index 0..1023
    int s = c * CHUNK;
    int e = min(s + CHUNK, T);

    const f4* tv4   = (const f4*)tv;
    const f4* rew4  = (const f4*)rew;
    const f4* disc4 = (const f4*)disc;
    const i4* st4   = (const i4*)st;

    f4 A  = {0.f, 0.f, 0.f, 0.f};
    f4 Bf = {1.f, 1.f, 1.f, 1.f};
    f4 tvn = tv4[(size_t)e * Q + q];          // tv[t+1] for first (highest-t) step
#pragma unroll 4
    for (int t = e - 1; t >= s; --t) {
        size_t i  = (size_t)t * Q + q;
        size_t i1 = i + Q;
        f4 d1  = disc4[i1] * GAMMA;
        f4 tvt = tv4[i];
        f4 r1  = rew4[i1];
        i4 stt = st4[i];
#pragma unroll
        for (int j = 0; j < 4; ++j) {
            float delta = r1[j] + d1[j] * tvn[j] - tvt[j];
            float wd    = d1[j] * TD_LAMBDA;
            float nl    = (stt[j] == 2) ? 0.f : 1.f;
            float a  = nl * delta;
            float bb = nl * wd;
            A[j]  = fmaf(bb, A[j], a);
            Bf[j] *= bb;
        }
        tvn = tvt;
    }
    ((f4*)AggA)[c * Q + q] = A;    // layout [c][b], quad-contiguous
    ((f4*)AggB)[c * Q + q] = Bf;
}

// Phase 2 (fused scan+replay): each block redundantly composes the suffix of
// chunk aggregates (2 MiB total, L2/L3-resident; loads independent of the
// accumulation chain so they pipeline) to get its right-boundary adv, then
// replays its chunk and emits the squared TD loss.
// Output is stored non-temporally (write-once, never re-read) so it doesn't
// evict the L3-hot input rows this kernel re-reads.
__global__ __launch_bounds__(256) void k_replay(
    const float* __restrict__ value, const float* __restrict__ tv,
    const float* __restrict__ rew, const int* __restrict__ st,
    const float* __restrict__ disc,
    const float* __restrict__ AggA, const float* __restrict__ AggB,
    float* __restrict__ out)
{
    int c = blockIdx.x >> 2;
    int g = blockIdx.x & 3;
    int q = (g << 8) + threadIdx.x;
    int s = c * CHUNK;
    int e = min(s + CHUNK, T);

    const f4* tv4   = (const f4*)tv;
    const f4* rew4  = (const f4*)rew;
    const f4* disc4 = (const f4*)disc;
    const f4* val4  = (const f4*)value;
    const i4* st4   = (const i4*)st;
    const f4* A4    = (const f4*)AggA;
    const f4* B4    = (const f4*)AggB;
    f4* out4 = (f4*)out;

    // Suffix walk: adv at t = e(c) is sum_{cc>c} (prod_{c<j<cc} B_j) * A_cc
    f4 S = {0.f, 0.f, 0.f, 0.f};
    f4 P = {1.f, 1.f, 1.f, 1.f};
    for (int cc = c + 1; cc < NCHUNK; ++cc) {
        f4 a = A4[cc * Q + q];
        f4 b = B4[cc * Q + q];
#pragma unroll
        for (int j = 0; j < 4; ++j) {
            S[j] = fmaf(P[j], a[j], S[j]);
            P[j] *= b[j];
        }
    }
    f4 adv = S;   // adv[e(c)]  (adv[T] = 0 terminal)

    if (c == NCHUNK - 1) {
        // tensor_extend_zero: last output row is zeros (d_out poisoned, must write)
        f4 z = {0.f, 0.f, 0.f, 0.f};
        __builtin_nontemporal_store(z, &out4[(size_t)T * Q + q]);
    }

    f4 tvn = tv4[(size_t)e * Q + q];
#pragma unroll 4
    for (int t = e - 1; t >= s; --t) {
        size_t i  = (size_t)t * Q + q;
        size_t i1 = i + Q;
        f4 d1  = disc4[i1] * GAMMA;
        f4 tvt = tv4[i];
        f4 r1  = rew4[i1];
        i4 stt = st4[i];
        f4 vv  = __builtin_nontemporal_load(&val4[i]);   // read-once stream
        f4 o;
#pragma unroll
        for (int j = 0; j < 4; ++j) {
            float delta = r1[j] + d1[j] * tvn[j] - tvt[j];
            float wd    = d1[j] * TD_LAMBDA;
            float nl    = (stt[j] == 2) ? 0.f : 1.f;
            adv[j] = nl * fmaf(wd, adv[j], delta);
            float td = adv[j] + tvt[j] - vv[j];
            o[j] = td * td;
        }
        __builtin_nontemporal_store(o, &out4[i]);
        tvn = tvt;
    }
}

extern "C" void kernel_launch(void* const* d_in, const int* in_sizes, int n_in,
                              void* d_out, int out_size, void* d_ws, size_t ws_size,
                              hipStream_t stream) {
    // setup_inputs order: value, target_value, reward, step_type, discount
    const float* value = (const float*)d_in[0];
    const float* tv    = (const float*)d_in[1];
    const float* rew   = (const float*)d_in[2];
    const int*   st    = (const int*)d_in[3];
    const float* disc  = (const float*)d_in[4];
    float* out = (float*)d_out;

    // Workspace: 2 arrays of NCHUNK*B floats = 2 MiB total
    float* AggA = (float*)d_ws;
    float* AggB = AggA + (size_t)NCHUNK * B;

    k_compose<<<NCHUNK * GPC, 256, 0, stream>>>(tv, rew, st, disc, AggA, AggB);
    k_replay<<<NCHUNK * GPC, 256, 0, stream>>>(value, tv, rew, st, disc, AggA, AggB, out);
}